// Round 3
// baseline (2106.889 us; speedup 1.0000x reference)
//
#include <hip/hip_runtime.h>

typedef __attribute__((ext_vector_type(8))) short bh8;
typedef __attribute__((ext_vector_type(4))) short bh4;
typedef __attribute__((ext_vector_type(4))) float f32x4;

__device__ __forceinline__ short f2bf(float f) {
  union { float f; unsigned u; } a; a.f = f;
  unsigned r = a.u + 0x7FFFu + ((a.u >> 16) & 1u);
  return (short)(r >> 16);
}

// ---------------------------------------------------------------------------
// Prep 1: x[b][c][s] (f32) -> xT[b][s][c] (bf16) for q,k,v. 64x64 tiles.
// grid (16,16,24): z = tensor*8 + b
// ---------------------------------------------------------------------------
__global__ __launch_bounds__(256) void transpose3(
    const float* __restrict__ q, const float* __restrict__ k, const float* __restrict__ v,
    short* __restrict__ qT, short* __restrict__ kT, short* __restrict__ vT) {
  int z = blockIdx.z; int tensor = z >> 3, b = z & 7;
  const float* src = tensor == 0 ? q : (tensor == 1 ? k : v);
  short* dst = tensor == 0 ? qT : (tensor == 1 ? kT : vT);
  src += (size_t)b * 1048576; dst += (size_t)b * 1048576;
  int row0 = blockIdx.y * 64;  // c
  int col0 = blockIdx.x * 64;  // s
  __shared__ short t[64][72];
  int tid = threadIdx.x;
#pragma unroll
  for (int i = 0; i < 2; ++i) {
    int cid = tid + i * 256;
    int r = cid >> 3, co = (cid & 7) * 8;
    const float* p = src + (size_t)(row0 + r) * 1024 + col0 + co;
    float4 f0 = *(const float4*)(p);
    float4 f1 = *(const float4*)(p + 4);
    t[co + 0][r] = f2bf(f0.x); t[co + 1][r] = f2bf(f0.y);
    t[co + 2][r] = f2bf(f0.z); t[co + 3][r] = f2bf(f0.w);
    t[co + 4][r] = f2bf(f1.x); t[co + 5][r] = f2bf(f1.y);
    t[co + 6][r] = f2bf(f1.z); t[co + 7][r] = f2bf(f1.w);
  }
  __syncthreads();
#pragma unroll
  for (int i = 0; i < 2; ++i) {
    int cid = tid + i * 256;
    int sr = cid >> 3, cc = (cid & 7) * 8;
    bh8 val = *(const bh8*)&t[sr][cc];
    *(bh8*)(dst + (size_t)(col0 + sr) * 1024 + row0 + cc) = val;
  }
}

// ---------------------------------------------------------------------------
// Prep 2: Wp[tap][o][c] (bf16) = W[o][c][tap] (f32).  grid (4096, 3)
// ---------------------------------------------------------------------------
__global__ __launch_bounds__(256) void wperm3(
    const float* __restrict__ Wq, const float* __restrict__ Wk, const float* __restrict__ Wv,
    short* __restrict__ WpQ, short* __restrict__ WpK, short* __restrict__ WpV) {
  int z = blockIdx.y;
  const float* W = z == 0 ? Wq : (z == 1 ? Wk : Wv);
  short* Wp = z == 0 ? WpQ : (z == 1 ? WpK : WpV);
  int idx = blockIdx.x * 256 + threadIdx.x;  // (o,c) flat, 0..1M
  const float* wsrc = W + (size_t)idx * 9;
#pragma unroll
  for (int t = 0; t < 9; ++t) Wp[(size_t)t * 1048576 + idx] = f2bf(wsrc[t]);
}

// ---------------------------------------------------------------------------
// Prep 3: Wo f32 -> bf16 flat.  grid (1024)
// ---------------------------------------------------------------------------
__global__ __launch_bounds__(256) void cvt_bf(const float* __restrict__ src,
                                              short* __restrict__ dst) {
  int idx = (blockIdx.x * 256 + threadIdx.x) * 4;
  float4 f = *(const float4*)(src + idx);
  bh4 o; o[0] = f2bf(f.x); o[1] = f2bf(f.y); o[2] = f2bf(f.z); o[3] = f2bf(f.w);
  *(bh4*)(dst + idx) = o;
}

// ---------------------------------------------------------------------------
// Fused conv3x3 implicit GEMM for Q,K,V. 128x128 tile, K = 9 taps x 1024 c.
// convSel >= 0: single conv (grid z = b, 8).  convSel < 0: fused (grid z = 24,
// conv = z>>3, b = z&7).  conv 0/1 (Q/K): A=W (m=o), B=x shifted (n=s),
// out[b][o][s].  conv 2 (V): A=x shifted (m=sp), B=W (n=o), out[b][sp][o].
// LDS rows padded 32->40 shorts (80B = 20 banks) to break 8-way conflicts.
// ---------------------------------------------------------------------------
__global__ __launch_bounds__(256, 5) void conv_gemm_all(
    const short* __restrict__ WpQ, const short* __restrict__ WpK, const short* __restrict__ WpV,
    const short* __restrict__ qT, const short* __restrict__ kT, const short* __restrict__ vT,
    short* __restrict__ cQ, short* __restrict__ cK, short* __restrict__ cVT,
    const float* __restrict__ bq, const float* __restrict__ bk, const float* __restrict__ bv,
    int convSel) {
  __shared__ short sA[128][40];
  __shared__ short sB[128][40];
  int tid = threadIdx.x, lane = tid & 63, wid = tid >> 6;
  int z = blockIdx.z;
  int conv = convSel >= 0 ? convSel : (z >> 3);
  int b = convSel >= 0 ? z : (z & 7);
  const short* Wp = conv == 0 ? WpQ : (conv == 1 ? WpK : WpV);
  const short* xT = conv == 0 ? qT : (conv == 1 ? kT : vT);
  short* out = conv == 0 ? cQ : (conv == 1 ? cK : cVT);
  const float* bias = conv == 0 ? bq : (conv == 1 ? bk : bv);
  int XisA = (conv == 2);
  int mbase = blockIdx.x * 128, nbase = blockIdx.y * 128;
  const short* xb = xT + (size_t)b * 1048576;
  f32x4 acc[4][4] = {};
  int wm = (wid >> 1) * 64, wn = (wid & 1) * 64;
  const bh8 zero8 = {0, 0, 0, 0, 0, 0, 0, 0};
  int row[2], co[2];
#pragma unroll
  for (int i = 0; i < 2; ++i) {
    int cid = tid + i * 256;
    row[i] = cid >> 2; co[i] = (cid & 3) * 8;
  }
  for (int tap = 0; tap < 9; ++tap) {
    int dy = tap / 3 - 1, dx = tap % 3 - 1;
    const short* wpt = Wp + (size_t)tap * 1048576;
    const short* xptr[2]; const short* wptr[2]; bool val[2];
#pragma unroll
    for (int i = 0; i < 2; ++i) {
      int arow = mbase + row[i], brow = nbase + row[i];
      int srow = XisA ? arow : brow;   // spatial-token row
      int wrow = XisA ? brow : arow;   // weight row
      int y = srow >> 5, x = srow & 31;
      int yy = y + dy, xx = x + dx;
      val[i] = ((unsigned)yy < 32u) & ((unsigned)xx < 32u);
      xptr[i] = xb + (size_t)(yy * 32 + xx) * 1024 + co[i];
      wptr[i] = wpt + (size_t)wrow * 1024 + co[i];
    }
    for (int kt = 0; kt < 1024; kt += 32) {
#pragma unroll
      for (int i = 0; i < 2; ++i) {
        bh8 xv = val[i] ? *(const bh8*)(xptr[i] + kt) : zero8;
        bh8 wv = *(const bh8*)(wptr[i] + kt);
        *(bh8*)&sA[row[i]][co[i]] = XisA ? xv : wv;
        *(bh8*)&sB[row[i]][co[i]] = XisA ? wv : xv;
      }
      __syncthreads();
      bh8 af[4], bfr[4];
#pragma unroll
      for (int mt = 0; mt < 4; ++mt)
        af[mt] = *(const bh8*)&sA[wm + mt * 16 + (lane & 15)][(lane >> 4) * 8];
#pragma unroll
      for (int nt = 0; nt < 4; ++nt)
        bfr[nt] = *(const bh8*)&sB[wn + nt * 16 + (lane & 15)][(lane >> 4) * 8];
#pragma unroll
      for (int mt = 0; mt < 4; ++mt)
#pragma unroll
        for (int nt = 0; nt < 4; ++nt)
          acc[mt][nt] = __builtin_amdgcn_mfma_f32_16x16x32_bf16(af[mt], bfr[nt], acc[mt][nt], 0, 0, 0);
      __syncthreads();
    }
  }
  size_t ob = (size_t)b * 1048576;
#pragma unroll
  for (int mt = 0; mt < 4; ++mt) {
#pragma unroll
    for (int nt = 0; nt < 4; ++nt) {
      int m0 = mbase + wm + mt * 16 + ((lane >> 4) << 2);
      int n = nbase + wn + nt * 16 + (lane & 15);
#pragma unroll
      for (int r = 0; r < 4; ++r) {
        float bv = bias[XisA ? n : (m0 + r)];
        out[ob + (size_t)(m0 + r) * 1024 + n] = f2bf(acc[mt][nt][r] + bv);
      }
    }
  }
}

// ---------------------------------------------------------------------------
// Attention per (qtile of 64 t-rows, head, b).  grid (16,16,8), 256 thr.
// Computes S^T tiles (m=s_tok, n=t); two-pass online softmax; P.V.
// Qc,Kc: [b][tok][spatial], VT: [b][spatial][tok], AO: [b][t][h*64+j]
// ---------------------------------------------------------------------------
__global__ __launch_bounds__(256) void attn(
    const short* __restrict__ Qc, const short* __restrict__ Kc,
    const short* __restrict__ VT, const int* __restrict__ mask,
    short* __restrict__ AO) {
  __shared__ short sQ[64][72];
  __shared__ short sK[128][72];
  __shared__ short sV[64][136];
  __shared__ short sP[64][136];
  int tid = threadIdx.x, lane = tid & 63, w = tid >> 6;
  int qbase = blockIdx.x * 64, h = blockIdx.y, b = blockIdx.z;
  int j0 = h * 64;
  const short* Qb = Qc + (size_t)b * 1048576;
  const short* Kb = Kc + (size_t)b * 1048576;
  const short* Vb = VT + (size_t)b * 1048576;
  const int* Mb = mask + (size_t)b * 1048576;
  const float scale = 0.125f;  // 1/sqrt(64)

#pragma unroll
  for (int i = 0; i < 2; ++i) {
    int cid = tid + i * 256;
    int row = cid >> 3, co = (cid & 7) * 8;
    *(bh8*)&sQ[row][co] = *(const bh8*)(Qb + (size_t)(qbase + row) * 1024 + j0 + co);
  }
  __syncthreads();

  int tg = qbase + w * 16 + (lane & 15);  // the t row this lane's stats cover
  float mrow = -3.0e38f, lrow = 0.0f;

  // ---- pass A: softmax stats over all 1024 s ----
  for (int st = 0; st < 8; ++st) {
#pragma unroll
    for (int i = 0; i < 4; ++i) {
      int cid = tid + i * 256;
      int row = cid >> 3, co = (cid & 7) * 8;
      *(bh8*)&sK[row][co] = *(const bh8*)(Kb + (size_t)(st * 128 + row) * 1024 + j0 + co);
    }
    __syncthreads();
    f32x4 sacc[8];
#pragma unroll
    for (int mt = 0; mt < 8; ++mt) {
      f32x4 a = {0.f, 0.f, 0.f, 0.f};
      bh8 kf = *(const bh8*)&sK[mt * 16 + (lane & 15)][(lane >> 4) * 8];
      bh8 qf = *(const bh8*)&sQ[w * 16 + (lane & 15)][(lane >> 4) * 8];
      a = __builtin_amdgcn_mfma_f32_16x16x32_bf16(kf, qf, a, 0, 0, 0);
      kf = *(const bh8*)&sK[mt * 16 + (lane & 15)][32 + (lane >> 4) * 8];
      qf = *(const bh8*)&sQ[w * 16 + (lane & 15)][32 + (lane >> 4) * 8];
      a = __builtin_amdgcn_mfma_f32_16x16x32_bf16(kf, qf, a, 0, 0, 0);
      sacc[mt] = a;
    }
    float tmax = -3.0e38f;
#pragma unroll
    for (int mt = 0; mt < 8; ++mt) {
      int sb = st * 128 + mt * 16 + ((lane >> 4) << 2);
      int4 mi = *(const int4*)(Mb + (size_t)tg * 1024 + sb);
      f32x4 vv;
      vv[0] = mi.x ? sacc[mt][0] * scale : -1e9f;
      vv[1] = mi.y ? sacc[mt][1] * scale : -1e9f;
      vv[2] = mi.z ? sacc[mt][2] * scale : -1e9f;
      vv[3] = mi.w ? sacc[mt][3] * scale : -1e9f;
      sacc[mt] = vv;
      tmax = fmaxf(tmax, fmaxf(fmaxf(vv[0], vv[1]), fmaxf(vv[2], vv[3])));
    }
    tmax = fmaxf(tmax, __shfl_xor(tmax, 16, 64));
    tmax = fmaxf(tmax, __shfl_xor(tmax, 32, 64));
    float mnew = fmaxf(mrow, tmax);
    float sum = 0.f;
#pragma unroll
    for (int mt = 0; mt < 8; ++mt)
#pragma unroll
      for (int r = 0; r < 4; ++r) sum += __expf(fminf(sacc[mt][r] - mnew, 0.f));
    sum += __shfl_xor(sum, 16, 64);
    sum += __shfl_xor(sum, 32, 64);
    lrow = lrow * __expf(fminf(mrow - mnew, 0.f)) + sum;
    mrow = mnew;
    __syncthreads();
  }
  float rl = 1.0f / lrow;

  // ---- pass B: P = exp(S-m)/l, O += P.V ----
  f32x4 oacc[4] = {};
  for (int st = 0; st < 8; ++st) {
#pragma unroll
    for (int i = 0; i < 4; ++i) {
      int cid = tid + i * 256;
      int row = cid >> 3, co = (cid & 7) * 8;
      *(bh8*)&sK[row][co] = *(const bh8*)(Kb + (size_t)(st * 128 + row) * 1024 + j0 + co);
      int vrow = cid >> 4, vco = (cid & 15) * 8;
      *(bh8*)&sV[vrow][vco] = *(const bh8*)(Vb + (size_t)(j0 + vrow) * 1024 + st * 128 + vco);
    }
    __syncthreads();
#pragma unroll
    for (int mt = 0; mt < 8; ++mt) {
      f32x4 a = {0.f, 0.f, 0.f, 0.f};
      bh8 kf = *(const bh8*)&sK[mt * 16 + (lane & 15)][(lane >> 4) * 8];
      bh8 qf = *(const bh8*)&sQ[w * 16 + (lane & 15)][(lane >> 4) * 8];
      a = __builtin_amdgcn_mfma_f32_16x16x32_bf16(kf, qf, a, 0, 0, 0);
      kf = *(const bh8*)&sK[mt * 16 + (lane & 15)][32 + (lane >> 4) * 8];
      qf = *(const bh8*)&sQ[w * 16 + (lane & 15)][32 + (lane >> 4) * 8];
      a = __builtin_amdgcn_mfma_f32_16x16x32_bf16(kf, qf, a, 0, 0, 0);
      int sb = mt * 16 + ((lane >> 4) << 2);
      int4 mi = *(const int4*)(Mb + (size_t)tg * 1024 + st * 128 + sb);
      bh4 p;
      p[0] = mi.x ? f2bf(__expf(fminf(a[0] * scale - mrow, 0.f)) * rl) : (short)0;
      p[1] = mi.y ? f2bf(__expf(fminf(a[1] * scale - mrow, 0.f)) * rl) : (short)0;
      p[2] = mi.z ? f2bf(__expf(fminf(a[2] * scale - mrow, 0.f)) * rl) : (short)0;
      p[3] = mi.w ? f2bf(__expf(fminf(a[3] * scale - mrow, 0.f)) * rl) : (short)0;
      *(bh4*)&sP[w * 16 + (lane & 15)][sb] = p;
    }
    __syncthreads();
#pragma unroll
    for (int k0 = 0; k0 < 4; ++k0) {
      bh8 pf = *(const bh8*)&sP[w * 16 + (lane & 15)][k0 * 32 + (lane >> 4) * 8];
#pragma unroll
      for (int nt = 0; nt < 4; ++nt) {
        bh8 vf = *(const bh8*)&sV[nt * 16 + (lane & 15)][k0 * 32 + (lane >> 4) * 8];
        oacc[nt] = __builtin_amdgcn_mfma_f32_16x16x32_bf16(pf, vf, oacc[nt], 0, 0, 0);
      }
    }
    __syncthreads();
  }
  size_t ob = (size_t)b * 1048576;
#pragma unroll
  for (int nt = 0; nt < 4; ++nt) {
    int j = nt * 16 + (lane & 15);
    int t0 = qbase + w * 16 + ((lane >> 4) << 2);
#pragma unroll
    for (int r = 0; r < 4; ++r)
      AO[ob + (size_t)(t0 + r) * 1024 + j0 + j] = f2bf(oacc[nt][r]);
  }
}

// ---------------------------------------------------------------------------
// Final projection: out[r][o] = sum_m A[r][m] * Wo[o][m] + bo[o]   (f32 out)
// A: [8192][1024] bf16, WoB: [1024][1024] bf16.  grid (64, 8)
// ---------------------------------------------------------------------------
__global__ __launch_bounds__(256) void gemm_bt(
    const short* __restrict__ A, const short* __restrict__ Bm,
    float* __restrict__ out, const float* __restrict__ bias) {
  __shared__ short sA[128][40];
  __shared__ short sB[128][40];
  int tid = threadIdx.x, lane = tid & 63, wid = tid >> 6;
  int mbase = blockIdx.x * 128, nbase = blockIdx.y * 128;
  f32x4 acc[4][4] = {};
  int wm = (wid >> 1) * 64, wn = (wid & 1) * 64;
  for (int kt = 0; kt < 1024; kt += 32) {
#pragma unroll
    for (int i = 0; i < 2; ++i) {
      int cid = tid + i * 256;
      int row = cid >> 2, co = (cid & 3) * 8;
      *(bh8*)&sA[row][co] = *(const bh8*)(A + (size_t)(mbase + row) * 1024 + kt + co);
      *(bh8*)&sB[row][co] = *(const bh8*)(Bm + (size_t)(nbase + row) * 1024 + kt + co);
    }
    __syncthreads();
    bh8 af[4], bfr[4];
#pragma unroll
    for (int mt = 0; mt < 4; ++mt)
      af[mt] = *(const bh8*)&sA[wm + mt * 16 + (lane & 15)][(lane >> 4) * 8];
#pragma unroll
    for (int nt = 0; nt < 4; ++nt)
      bfr[nt] = *(const bh8*)&sB[wn + nt * 16 + (lane & 15)][(lane >> 4) * 8];
#pragma unroll
    for (int mt = 0; mt < 4; ++mt)
#pragma unroll
      for (int nt = 0; nt < 4; ++nt)
        acc[mt][nt] = __builtin_amdgcn_mfma_f32_16x16x32_bf16(af[mt], bfr[nt], acc[mt][nt], 0, 0, 0);
    __syncthreads();
  }
#pragma unroll
  for (int mt = 0; mt < 4; ++mt) {
#pragma unroll
    for (int nt = 0; nt < 4; ++nt) {
      int m0 = mbase + wm + mt * 16 + ((lane >> 4) << 2);
      int n = nbase + wn + nt * 16 + (lane & 15);
      float bv = bias[n];
#pragma unroll
      for (int r = 0; r < 4; ++r)
        out[(size_t)(m0 + r) * 1024 + n] = acc[mt][nt][r] + bv;
    }
  }
}

// ---------------------------------------------------------------------------
extern "C" void kernel_launch(void* const* d_in, const int* in_sizes, int n_in,
                              void* d_out, int out_size, void* d_ws, size_t ws_size,
                              hipStream_t stream) {
  (void)in_sizes; (void)n_in; (void)out_size;
  const float* q    = (const float*)d_in[0];
  const float* k    = (const float*)d_in[1];
  const float* v    = (const float*)d_in[2];
  const float* Wq   = (const float*)d_in[3];
  const float* bq   = (const float*)d_in[4];
  const float* Wk   = (const float*)d_in[5];
  const float* bk   = (const float*)d_in[6];
  const float* Wv   = (const float*)d_in[7];
  const float* bv   = (const float*)d_in[8];
  const float* Wo   = (const float*)d_in[9];
  const float* bo   = (const float*)d_in[10];
  const int*   mask = (const int*)d_in[11];
  float* out = (float*)d_out;
  char* ws = (char*)d_ws;

  const size_t MB = 1048576;
  short* qT  = (short*)(ws);                 // 16MB
  short* kT  = (short*)(ws + 16 * MB);       // 16MB
  short* vT  = (short*)(ws + 32 * MB);       // 16MB
  short* WpQ = (short*)(ws + 48 * MB);       // 18MB
  short* WpK = (short*)(ws + 66 * MB);       // 18MB
  short* WpV = (short*)(ws + 84 * MB);       // 18MB
  short* cQ  = (short*)(ws + 102 * MB);      // 16MB

  bool fused = ws_size >= 152 * MB;
  short *cK, *cVT, *WoB, *AO;
  if (fused) {
    cK  = (short*)(ws + 118 * MB);           // 16MB
    cVT = (short*)(ws + 134 * MB);           // 16MB
    WoB = (short*)(ws + 150 * MB);           // 2MB
    AO  = qT;   // qT dead after conv dispatch  (high-water: 152MB)
  } else {
    WoB = (short*)(ws + 118 * MB);           // 2MB
    cK  = qT;   // sequential: qT dead after conv Q
    cVT = kT;   // kT dead after conv K
    AO  = vT;   // vT dead after conv V        (high-water: 120MB)
  }

  transpose3<<<dim3(16, 16, 24), dim3(256), 0, stream>>>(q, k, v, qT, kT, vT);
  wperm3<<<dim3(4096, 3), dim3(256), 0, stream>>>(Wq, Wk, Wv, WpQ, WpK, WpV);
  cvt_bf<<<dim3(1024), dim3(256), 0, stream>>>(Wo, WoB);
  if (fused) {
    conv_gemm_all<<<dim3(8, 8, 24), dim3(256), 0, stream>>>(
        WpQ, WpK, WpV, qT, kT, vT, cQ, cK, cVT, bq, bk, bv, -1);
  } else {
    conv_gemm_all<<<dim3(8, 8, 8), dim3(256), 0, stream>>>(
        WpQ, WpK, WpV, qT, kT, vT, cQ, cK, cVT, bq, bk, bv, 0);
    conv_gemm_all<<<dim3(8, 8, 8), dim3(256), 0, stream>>>(
        WpQ, WpK, WpV, qT, kT, vT, cQ, cK, cVT, bq, bk, bv, 1);
    conv_gemm_all<<<dim3(8, 8, 8), dim3(256), 0, stream>>>(
        WpQ, WpK, WpV, qT, kT, vT, cQ, cK, cVT, bq, bk, bv, 2);
  }
  attn<<<dim3(16, 16, 8), dim3(256), 0, stream>>>(cQ, cK, cVT, mask, AO);
  gemm_bt<<<dim3(64, 8), dim3(256), 0, stream>>>(AO, WoB, out, bo);
}

// Round 4
// 974.592 us; speedup vs baseline: 2.1618x; 2.1618x over previous
//
#include <hip/hip_runtime.h>

typedef __attribute__((ext_vector_type(8))) short bh8;
typedef __attribute__((ext_vector_type(4))) short bh4;
typedef __attribute__((ext_vector_type(4))) float f32x4;

__device__ __forceinline__ short f2bf(float f) {
  union { float f; unsigned u; } a; a.f = f;
  unsigned r = a.u + 0x7FFFu + ((a.u >> 16) & 1u);
  return (short)(r >> 16);
}

// async global->LDS DMA, 16B per lane; LDS dest must be wave-uniform base + lane*16
__device__ __forceinline__ void g2l16(const short* g, short* l) {
  __builtin_amdgcn_global_load_lds(
      (const __attribute__((address_space(1))) void*)g,
      (__attribute__((address_space(3))) void*)l, 16, 0, 0);
}

// ---------------------------------------------------------------------------
// zero the padded-halo buffers (borders must be 0; ws is poisoned 0xAA)
// ---------------------------------------------------------------------------
__global__ __launch_bounds__(256) void zero16(short* p, int n8) {
  int i = blockIdx.x * 256 + threadIdx.x;
  if (i < n8) { bh8 z = {0, 0, 0, 0, 0, 0, 0, 0}; ((bh8*)p)[i] = z; }
}

// ---------------------------------------------------------------------------
// Prep 1: x[b][c][32*32] (f32) -> xP[b][(y+1)*34+(x+1)][c] (bf16), halo=0.
// grid (16,16,24): z = tensor*8 + b
// ---------------------------------------------------------------------------
__global__ __launch_bounds__(256) void transpose3(
    const float* __restrict__ q, const float* __restrict__ k, const float* __restrict__ v,
    short* __restrict__ qP, short* __restrict__ kP, short* __restrict__ vP) {
  int z = blockIdx.z; int tensor = z >> 3, b = z & 7;
  const float* src = tensor == 0 ? q : (tensor == 1 ? k : v);
  short* dst = tensor == 0 ? qP : (tensor == 1 ? kP : vP);
  src += (size_t)b * 1048576; dst += (size_t)b * 1183744;  // 1156*1024
  int row0 = blockIdx.y * 64;  // c
  int col0 = blockIdx.x * 64;  // s
  __shared__ short t[64][72];
  int tid = threadIdx.x;
#pragma unroll
  for (int i = 0; i < 2; ++i) {
    int cid = tid + i * 256;
    int r = cid >> 3, co = (cid & 7) * 8;
    const float* p = src + (size_t)(row0 + r) * 1024 + col0 + co;
    float4 f0 = *(const float4*)(p);
    float4 f1 = *(const float4*)(p + 4);
    t[co + 0][r] = f2bf(f0.x); t[co + 1][r] = f2bf(f0.y);
    t[co + 2][r] = f2bf(f0.z); t[co + 3][r] = f2bf(f0.w);
    t[co + 4][r] = f2bf(f1.x); t[co + 5][r] = f2bf(f1.y);
    t[co + 6][r] = f2bf(f1.z); t[co + 7][r] = f2bf(f1.w);
  }
  __syncthreads();
#pragma unroll
  for (int i = 0; i < 2; ++i) {
    int cid = tid + i * 256;
    int sr = cid >> 3, cc = (cid & 7) * 8;
    bh8 val = *(const bh8*)&t[sr][cc];
    int tok = col0 + sr;
    int pr = ((tok >> 5) + 1) * 34 + (tok & 31) + 1;
    *(bh8*)(dst + (size_t)pr * 1024 + row0 + cc) = val;
  }
}

// ---------------------------------------------------------------------------
// Prep 2: Wp[tap][o][c] (bf16) = W[o][c][tap] (f32).  grid (4096, 3)
// ---------------------------------------------------------------------------
__global__ __launch_bounds__(256) void wperm3(
    const float* __restrict__ Wq, const float* __restrict__ Wk, const float* __restrict__ Wv,
    short* __restrict__ WpQ, short* __restrict__ WpK, short* __restrict__ WpV) {
  int z = blockIdx.y;
  const float* W = z == 0 ? Wq : (z == 1 ? Wk : Wv);
  short* Wp = z == 0 ? WpQ : (z == 1 ? WpK : WpV);
  int idx = blockIdx.x * 256 + threadIdx.x;  // (o,c) flat, 0..1M
  const float* wsrc = W + (size_t)idx * 9;
#pragma unroll
  for (int t = 0; t < 9; ++t) Wp[(size_t)t * 1048576 + idx] = f2bf(wsrc[t]);
}

// ---------------------------------------------------------------------------
// Prep 3: Wo f32 -> bf16 flat.  grid (1024)
// ---------------------------------------------------------------------------
__global__ __launch_bounds__(256) void cvt_bf(const float* __restrict__ src,
                                              short* __restrict__ dst) {
  int idx = (blockIdx.x * 256 + threadIdx.x) * 4;
  float4 f = *(const float4*)(src + idx);
  bh4 o; o[0] = f2bf(f.x); o[1] = f2bf(f.y); o[2] = f2bf(f.z); o[3] = f2bf(f.w);
  *(bh4*)(dst + idx) = o;
}

// ---------------------------------------------------------------------------
// Prep 4: pack mask int32 -> bits. word idx = (b*1024 + t)*32 + (s>>5)
// grid (1024), 256 thr: one word per thread (262144 words)
// ---------------------------------------------------------------------------
__global__ __launch_bounds__(256) void mask_pack(const int* __restrict__ m,
                                                 unsigned* __restrict__ mp) {
  int idx = blockIdx.x * 256 + threadIdx.x;
  const int* src = m + (size_t)idx * 32;
  unsigned wv = 0;
#pragma unroll
  for (int j = 0; j < 32; j += 4) {
    int4 a = *(const int4*)(src + j);
    wv |= ((unsigned)(a.x & 1) << j) | ((unsigned)(a.y & 1) << (j + 1)) |
          ((unsigned)(a.z & 1) << (j + 2)) | ((unsigned)(a.w & 1) << (j + 3));
  }
  mp[idx] = wv;
}

// ---------------------------------------------------------------------------
// Fused conv3x3 implicit GEMM (Q,K,V). 128x128 tile, K = 9 taps x 1024 c.
// Staging via global_load_lds (16B/lane, unpadded 64B LDS rows). Halo layout
// makes every tap shift a pure pointer offset (no predication).
// conv 0/1 (Q/K): A=W (m=o), B=x (n=token), out[b][o][s].
// conv 2   (V):   A=x (m=token), B=W (n=o), out[b][token][o].
// convSel>=0: z=b (grid z=8); convSel<0: fused, z=conv*8+b (grid z=24).
// ---------------------------------------------------------------------------
__global__ __launch_bounds__(256) void conv_gemm_all(
    const short* __restrict__ WpQ, const short* __restrict__ WpK, const short* __restrict__ WpV,
    const short* __restrict__ xPq, const short* __restrict__ xPk, const short* __restrict__ xPv,
    short* __restrict__ cQ, short* __restrict__ cK, short* __restrict__ cVT,
    const float* __restrict__ bq, const float* __restrict__ bk, const float* __restrict__ bv,
    int convSel) {
  __shared__ short sA[4096];  // 128 rows x 32 shorts (64B), DMA-contiguous
  __shared__ short sB[4096];
  int tid = threadIdx.x, lane = tid & 63, w = tid >> 6;
  int z = blockIdx.z;
  int conv = convSel >= 0 ? convSel : (z >> 3);
  int b = convSel >= 0 ? z : (z & 7);
  const short* Wp = conv == 0 ? WpQ : (conv == 1 ? WpK : WpV);
  const short* xP = conv == 0 ? xPq : (conv == 1 ? xPk : xPv);
  short* out = conv == 0 ? cQ : (conv == 1 ? cK : cVT);
  const float* bias = conv == 0 ? bq : (conv == 1 ? bk : bv);
  int XisA = (conv == 2);
  int mbase = blockIdx.x * 128, nbase = blockIdx.y * 128;
  const short* xb = xP + (size_t)b * 1183744;
  int wbase = XisA ? nbase : mbase;  // weight-row tile base
  int sbase = XisA ? mbase : nbase;  // spatial-token tile base
  short* sW = XisA ? sB : sA;
  short* sX = XisA ? sA : sB;

  int colsh = (lane & 3) * 8;
  int ldsoff[2]; const short* wp0[2]; const short* xp0[2];
#pragma unroll
  for (int i = 0; i < 2; ++i) {
    int row = 32 * w + 16 * i + (lane >> 2);
    ldsoff[i] = (2 * w + i) * 512 + lane * 8;  // byte = chunk*1024 + lane*16
    wp0[i] = Wp + (size_t)(wbase + row) * 1024 + colsh;
    int tok = sbase + row;
    int pr0 = ((tok >> 5) + 1) * 34 + (tok & 31) + 1;
    xp0[i] = xb + (size_t)pr0 * 1024 + colsh;
  }
  f32x4 acc[4][4] = {};
  int wm = (w >> 1) * 64, wn = (w & 1) * 64;
  for (int tap = 0; tap < 9; ++tap) {
    int dOff = (tap / 3 - 1) * 34 + (tap % 3 - 1);  // padded-row shift
    size_t wtap = (size_t)tap * 1048576;
    for (int kt = 0; kt < 1024; kt += 32) {
#pragma unroll
      for (int i = 0; i < 2; ++i) {
        g2l16(wp0[i] + wtap + kt, sW + ldsoff[i]);
        g2l16(xp0[i] + (ptrdiff_t)dOff * 1024 + kt, sX + ldsoff[i]);
      }
      __syncthreads();
      bh8 af[4], bfr[4];
#pragma unroll
      for (int mt = 0; mt < 4; ++mt)
        af[mt] = *(const bh8*)&sA[(wm + mt * 16 + (lane & 15)) * 32 + (lane >> 4) * 8];
#pragma unroll
      for (int nt = 0; nt < 4; ++nt)
        bfr[nt] = *(const bh8*)&sB[(wn + nt * 16 + (lane & 15)) * 32 + (lane >> 4) * 8];
#pragma unroll
      for (int mt = 0; mt < 4; ++mt)
#pragma unroll
        for (int nt = 0; nt < 4; ++nt)
          acc[mt][nt] = __builtin_amdgcn_mfma_f32_16x16x32_bf16(af[mt], bfr[nt], acc[mt][nt], 0, 0, 0);
      __syncthreads();
    }
  }
  size_t ob = (size_t)b * 1048576;
#pragma unroll
  for (int mt = 0; mt < 4; ++mt) {
#pragma unroll
    for (int nt = 0; nt < 4; ++nt) {
      int m0 = mbase + wm + mt * 16 + ((lane >> 4) << 2);
      int n = nbase + wn + nt * 16 + (lane & 15);
#pragma unroll
      for (int r = 0; r < 4; ++r) {
        float bv = bias[XisA ? n : (m0 + r)];
        out[ob + (size_t)(m0 + r) * 1024 + n] = f2bf(acc[mt][nt][r] + bv);
      }
    }
  }
}

// ---------------------------------------------------------------------------
// Attention per (qtile of 64 t-rows, head, b).  grid (16,16,8), 256 thr.
// S^T tiles (m=s_tok, n=t); two-pass online softmax; P.V. Bit-packed mask.
// Qc,Kc: [b][tok][spatial], VT: [b][spatial][tok], AO: [b][t][h*64+j]
// ---------------------------------------------------------------------------
__global__ __launch_bounds__(256) void attn(
    const short* __restrict__ Qc, const short* __restrict__ Kc,
    const short* __restrict__ VT, const unsigned* __restrict__ Mp,
    short* __restrict__ AO) {
  __shared__ short sQ[64][72];
  __shared__ short sK[128][72];
  __shared__ short sV[64][136];
  __shared__ short sP[64][136];
  int tid = threadIdx.x, lane = tid & 63, w = tid >> 6;
  int qbase = blockIdx.x * 64, h = blockIdx.y, b = blockIdx.z;
  int j0 = h * 64;
  const short* Qb = Qc + (size_t)b * 1048576;
  const short* Kb = Kc + (size_t)b * 1048576;
  const short* Vb = VT + (size_t)b * 1048576;
  const unsigned* Mpb = Mp + (size_t)b * 32768;
  const float scale = 0.125f;  // 1/sqrt(64)

#pragma unroll
  for (int i = 0; i < 2; ++i) {
    int cid = tid + i * 256;
    int row = cid >> 3, co = (cid & 7) * 8;
    *(bh8*)&sQ[row][co] = *(const bh8*)(Qb + (size_t)(qbase + row) * 1024 + j0 + co);
  }
  __syncthreads();

  int tg = qbase + w * 16 + (lane & 15);  // the t row this lane's stats cover
  float mrow = -3.0e38f, lrow = 0.0f;

  // ---- pass A: softmax stats over all 1024 s ----
  for (int st = 0; st < 8; ++st) {
#pragma unroll
    for (int i = 0; i < 4; ++i) {
      int cid = tid + i * 256;
      int row = cid >> 3, co = (cid & 7) * 8;
      *(bh8*)&sK[row][co] = *(const bh8*)(Kb + (size_t)(st * 128 + row) * 1024 + j0 + co);
    }
    __syncthreads();
    f32x4 sacc[8];
#pragma unroll
    for (int mt = 0; mt < 8; ++mt) {
      f32x4 a = {0.f, 0.f, 0.f, 0.f};
      bh8 kf = *(const bh8*)&sK[mt * 16 + (lane & 15)][(lane >> 4) * 8];
      bh8 qf = *(const bh8*)&sQ[w * 16 + (lane & 15)][(lane >> 4) * 8];
      a = __builtin_amdgcn_mfma_f32_16x16x32_bf16(kf, qf, a, 0, 0, 0);
      kf = *(const bh8*)&sK[mt * 16 + (lane & 15)][32 + (lane >> 4) * 8];
      qf = *(const bh8*)&sQ[w * 16 + (lane & 15)][32 + (lane >> 4) * 8];
      a = __builtin_amdgcn_mfma_f32_16x16x32_bf16(kf, qf, a, 0, 0, 0);
      sacc[mt] = a;
    }
    float tmax = -3.0e38f;
#pragma unroll
    for (int mt = 0; mt < 8; ++mt) {
      int sb = st * 128 + mt * 16 + ((lane >> 4) << 2);
      unsigned mw = Mpb[(size_t)tg * 32 + (sb >> 5)] >> (sb & 31);
      f32x4 vv;
      vv[0] = (mw & 1u) ? sacc[mt][0] * scale : -1e9f;
      vv[1] = (mw & 2u) ? sacc[mt][1] * scale : -1e9f;
      vv[2] = (mw & 4u) ? sacc[mt][2] * scale : -1e9f;
      vv[3] = (mw & 8u) ? sacc[mt][3] * scale : -1e9f;
      sacc[mt] = vv;
      tmax = fmaxf(tmax, fmaxf(fmaxf(vv[0], vv[1]), fmaxf(vv[2], vv[3])));
    }
    tmax = fmaxf(tmax, __shfl_xor(tmax, 16, 64));
    tmax = fmaxf(tmax, __shfl_xor(tmax, 32, 64));
    float mnew = fmaxf(mrow, tmax);
    float sum = 0.f;
#pragma unroll
    for (int mt = 0; mt < 8; ++mt)
#pragma unroll
      for (int r = 0; r < 4; ++r) sum += __expf(fminf(sacc[mt][r] - mnew, 0.f));
    sum += __shfl_xor(sum, 16, 64);
    sum += __shfl_xor(sum, 32, 64);
    lrow = lrow * __expf(fminf(mrow - mnew, 0.f)) + sum;
    mrow = mnew;
    __syncthreads();
  }
  float rl = 1.0f / lrow;

  // ---- pass B: P = exp(S-m)/l, O += P.V ----
  f32x4 oacc[4] = {};
  for (int st = 0; st < 8; ++st) {
#pragma unroll
    for (int i = 0; i < 4; ++i) {
      int cid = tid + i * 256;
      int row = cid >> 3, co = (cid & 7) * 8;
      *(bh8*)&sK[row][co] = *(const bh8*)(Kb + (size_t)(st * 128 + row) * 1024 + j0 + co);
      int vrow = cid >> 4, vco = (cid & 15) * 8;
      *(bh8*)&sV[vrow][vco] = *(const bh8*)(Vb + (size_t)(j0 + vrow) * 1024 + st * 128 + vco);
    }
    __syncthreads();
#pragma unroll
    for (int mt = 0; mt < 8; ++mt) {
      f32x4 a = {0.f, 0.f, 0.f, 0.f};
      bh8 kf = *(const bh8*)&sK[mt * 16 + (lane & 15)][(lane >> 4) * 8];
      bh8 qf = *(const bh8*)&sQ[w * 16 + (lane & 15)][(lane >> 4) * 8];
      a = __builtin_amdgcn_mfma_f32_16x16x32_bf16(kf, qf, a, 0, 0, 0);
      kf = *(const bh8*)&sK[mt * 16 + (lane & 15)][32 + (lane >> 4) * 8];
      qf = *(const bh8*)&sQ[w * 16 + (lane & 15)][32 + (lane >> 4) * 8];
      a = __builtin_amdgcn_mfma_f32_16x16x32_bf16(kf, qf, a, 0, 0, 0);
      int sb = mt * 16 + ((lane >> 4) << 2);
      unsigned mw = Mpb[(size_t)tg * 32 + ((st * 128 + sb) >> 5)] >> (sb & 31);
      bh4 p;
      p[0] = (mw & 1u) ? f2bf(__expf(fminf(a[0] * scale - mrow, 0.f)) * rl) : (short)0;
      p[1] = (mw & 2u) ? f2bf(__expf(fminf(a[1] * scale - mrow, 0.f)) * rl) : (short)0;
      p[2] = (mw & 4u) ? f2bf(__expf(fminf(a[2] * scale - mrow, 0.f)) * rl) : (short)0;
      p[3] = (mw & 8u) ? f2bf(__expf(fminf(a[3] * scale - mrow, 0.f)) * rl) : (short)0;
      *(bh4*)&sP[w * 16 + (lane & 15)][sb] = p;
    }
    __syncthreads();
#pragma unroll
    for (int k0 = 0; k0 < 4; ++k0) {
      bh8 pf = *(const bh8*)&sP[w * 16 + (lane & 15)][k0 * 32 + (lane >> 4) * 8];
#pragma unroll
      for (int nt = 0; nt < 4; ++nt) {
        bh8 vf = *(const bh8*)&sV[nt * 16 + (lane & 15)][k0 * 32 + (lane >> 4) * 8];
        oacc[nt] = __builtin_amdgcn_mfma_f32_16x16x32_bf16(pf, vf, oacc[nt], 0, 0, 0);
      }
    }
    __syncthreads();
  }
  size_t ob = (size_t)b * 1048576;
#pragma unroll
  for (int nt = 0; nt < 4; ++nt) {
    int j = nt * 16 + (lane & 15);
    int t0 = qbase + w * 16 + ((lane >> 4) << 2);
#pragma unroll
    for (int r = 0; r < 4; ++r)
      AO[ob + (size_t)(t0 + r) * 1024 + j0 + j] = f2bf(oacc[nt][r]);
  }
}

// ---------------------------------------------------------------------------
// Final projection: out[r][o] = sum_m A[r][m] * Wo[o][m] + bo[o]   (f32 out)
// A: [8192][1024] bf16, WoB: [1024][1024] bf16.  grid (64, 8).  DMA staging.
// ---------------------------------------------------------------------------
__global__ __launch_bounds__(256) void gemm_bt(
    const short* __restrict__ A, const short* __restrict__ Bm,
    float* __restrict__ out, const float* __restrict__ bias) {
  __shared__ short sA[4096];
  __shared__ short sB[4096];
  int tid = threadIdx.x, lane = tid & 63, w = tid >> 6;
  int mbase = blockIdx.x * 128, nbase = blockIdx.y * 128;
  int colsh = (lane & 3) * 8;
  int ldsoff[2]; const short* ap[2]; const short* bp[2];
#pragma unroll
  for (int i = 0; i < 2; ++i) {
    int row = 32 * w + 16 * i + (lane >> 2);
    ldsoff[i] = (2 * w + i) * 512 + lane * 8;
    ap[i] = A + (size_t)(mbase + row) * 1024 + colsh;
    bp[i] = Bm + (size_t)(nbase + row) * 1024 + colsh;
  }
  f32x4 acc[4][4] = {};
  int wm = (w >> 1) * 64, wn = (w & 1) * 64;
  for (int kt = 0; kt < 1024; kt += 32) {
#pragma unroll
    for (int i = 0; i < 2; ++i) {
      g2l16(ap[i] + kt, sA + ldsoff[i]);
      g2l16(bp[i] + kt, sB + ldsoff[i]);
    }
    __syncthreads();
    bh8 af[4], bfr[4];
#pragma unroll
    for (int mt = 0; mt < 4; ++mt)
      af[mt] = *(const bh8*)&sA[(wm + mt * 16 + (lane & 15)) * 32 + (lane >> 4) * 8];
#pragma unroll
    for (int nt = 0; nt < 4; ++nt)
      bfr[nt] = *(const bh8*)&sB[(wn + nt * 16 + (lane & 15)) * 32 + (lane >> 4) * 8];
#pragma unroll
    for (int mt = 0; mt < 4; ++mt)
#pragma unroll
      for (int nt = 0; nt < 4; ++nt)
        acc[mt][nt] = __builtin_amdgcn_mfma_f32_16x16x32_bf16(af[mt], bfr[nt], acc[mt][nt], 0, 0, 0);
    __syncthreads();
  }
#pragma unroll
  for (int mt = 0; mt < 4; ++mt) {
#pragma unroll
    for (int nt = 0; nt < 4; ++nt) {
      int m0 = mbase + wm + mt * 16 + ((lane >> 4) << 2);
      int n = nbase + wn + nt * 16 + (lane & 15);
      float bv = bias[n];
#pragma unroll
      for (int r = 0; r < 4; ++r)
        out[(size_t)(m0 + r) * 1024 + n] = acc[mt][nt][r] + bv;
    }
  }
}

// ---------------------------------------------------------------------------
extern "C" void kernel_launch(void* const* d_in, const int* in_sizes, int n_in,
                              void* d_out, int out_size, void* d_ws, size_t ws_size,
                              hipStream_t stream) {
  (void)in_sizes; (void)n_in; (void)out_size;
  const float* q    = (const float*)d_in[0];
  const float* k    = (const float*)d_in[1];
  const float* v    = (const float*)d_in[2];
  const float* Wq   = (const float*)d_in[3];
  const float* bq   = (const float*)d_in[4];
  const float* Wk   = (const float*)d_in[5];
  const float* bk   = (const float*)d_in[6];
  const float* Wv   = (const float*)d_in[7];
  const float* bv   = (const float*)d_in[8];
  const float* Wo   = (const float*)d_in[9];
  const float* bo   = (const float*)d_in[10];
  const int*   mask = (const int*)d_in[11];
  float* out = (float*)d_out;
  char* ws = (char*)d_ws;

  const size_t XPE = 1156ull * 1024 * 8;      // padded tensor elems (9,469,952)
  const size_t XPB = XPE * 2;                 // 18,939,904 B
  const size_t WPE = 9ull * 1048576;          // Wp elems
  short* xPq = (short*)ws;
  short* xPk = xPq + XPE;
  short* xPv = xPk + XPE;
  short* WpQ = (short*)(ws + 3 * XPB);
  short* WpK = WpQ + WPE;
  short* WpV = WpK + WPE;
  char* p2 = ws + 3 * XPB + 3 * WPE * 2;      // 113,442,816

  bool fused = ws_size >= 167000000ull;
  short *cQ, *cK, *cVT, *WoB, *AO; unsigned* Mpk;
  if (fused) {
    cQ  = (short*)(p2);
    cK  = (short*)(p2 + 16777216);
    cVT = (short*)(p2 + 33554432);
    WoB = (short*)(p2 + 50331648);
    Mpk = (unsigned*)(p2 + 52428800);
    AO  = xPq;                                 // dead after conv (hi-water ~159.3MB)
  } else {
    cQ  = (short*)(p2);
    WoB = (short*)(p2 + 16777216);
    Mpk = (unsigned*)(p2 + 18874368);
    cK  = xPq;   // sequential: xPq dead after conv Q
    cVT = xPk;   // xPk dead after conv K
    AO  = xPv;   // xPv dead after conv V      (hi-water ~127.2MB)
  }

  zero16<<<dim3(13872), dim3(256), 0, stream>>>(xPq, 3551232);
  transpose3<<<dim3(16, 16, 24), dim3(256), 0, stream>>>(q, k, v, xPq, xPk, xPv);
  wperm3<<<dim3(4096, 3), dim3(256), 0, stream>>>(Wq, Wk, Wv, WpQ, WpK, WpV);
  cvt_bf<<<dim3(1024), dim3(256), 0, stream>>>(Wo, WoB);
  mask_pack<<<dim3(1024), dim3(256), 0, stream>>>(mask, Mpk);
  if (fused) {
    conv_gemm_all<<<dim3(8, 8, 24), dim3(256), 0, stream>>>(
        WpQ, WpK, WpV, xPq, xPk, xPv, cQ, cK, cVT, bq, bk, bv, -1);
  } else {
    conv_gemm_all<<<dim3(8, 8, 8), dim3(256), 0, stream>>>(
        WpQ, WpK, WpV, xPq, xPk, xPv, cQ, cK, cVT, bq, bk, bv, 0);
    conv_gemm_all<<<dim3(8, 8, 8), dim3(256), 0, stream>>>(
        WpQ, WpK, WpV, xPq, xPk, xPv, cQ, cK, cVT, bq, bk, bv, 1);
    conv_gemm_all<<<dim3(8, 8, 8), dim3(256), 0, stream>>>(
        WpQ, WpK, WpV, xPq, xPk, xPv, cQ, cK, cVT, bq, bk, bv, 2);
  }
  attn<<<dim3(16, 16, 8), dim3(256), 0, stream>>>(cQ, cK, cVT, Mpk, AO);
  gemm_bt<<<dim3(64, 8), dim3(256), 0, stream>>>(AO, WoB, out, bo);
}

// Round 5
// 925.578 us; speedup vs baseline: 2.2763x; 1.0530x over previous
//
#include <hip/hip_runtime.h>

typedef __attribute__((ext_vector_type(8))) short bh8;
typedef __attribute__((ext_vector_type(4))) short bh4;
typedef __attribute__((ext_vector_type(4))) float f32x4;

__device__ __forceinline__ short f2bf(float f) {
  union { float f; unsigned u; } a; a.f = f;
  unsigned r = a.u + 0x7FFFu + ((a.u >> 16) & 1u);
  return (short)(r >> 16);
}

// async global->LDS DMA, 16B per lane; LDS dest must be wave-uniform base + lane*16
__device__ __forceinline__ void g2l16(const short* g, short* l) {
  __builtin_amdgcn_global_load_lds(
      (const __attribute__((address_space(1))) void*)g,
      (__attribute__((address_space(3))) void*)l, 16, 0, 0);
}

// ---------------------------------------------------------------------------
// Zero only the 132 halo rows of each padded tensor (q,k,v are contiguous).
// grid (66, 24): 2 rows per block; 128 lanes x 8 shorts cover a 1024-row.
// ---------------------------------------------------------------------------
__global__ __launch_bounds__(256) void zero_halo(short* __restrict__ xP) {
  int z = blockIdx.y;  // (tensor*8 + b), buffers contiguous
  short* base = xP + (size_t)z * 1183744;
  int ri = blockIdx.x * 2 + (threadIdx.x >> 7);  // 0..131
  int row;
  if (ri < 34) row = ri;                           // y = 0
  else if (ri < 68) row = 1122 + (ri - 34);        // y = 33
  else { int j = ri - 68; int y = (j >> 1) + 1; int x = (j & 1) ? 33 : 0; row = y * 34 + x; }
  int col = (threadIdx.x & 127) * 8;
  bh8 zv = {0, 0, 0, 0, 0, 0, 0, 0};
  *(bh8*)(base + (size_t)row * 1024 + col) = zv;
}

// ---------------------------------------------------------------------------
// Prep 1: x[b][c][32*32] (f32) -> xP[b][(y+1)*34+(x+1)][c] (bf16), halo=0.
// grid (16,16,24): z = tensor*8 + b
// ---------------------------------------------------------------------------
__global__ __launch_bounds__(256) void transpose3(
    const float* __restrict__ q, const float* __restrict__ k, const float* __restrict__ v,
    short* __restrict__ qP, short* __restrict__ kP, short* __restrict__ vP) {
  int z = blockIdx.z; int tensor = z >> 3, b = z & 7;
  const float* src = tensor == 0 ? q : (tensor == 1 ? k : v);
  short* dst = tensor == 0 ? qP : (tensor == 1 ? kP : vP);
  src += (size_t)b * 1048576; dst += (size_t)b * 1183744;  // 1156*1024
  int row0 = blockIdx.y * 64;  // c
  int col0 = blockIdx.x * 64;  // s
  __shared__ short t[64][72];
  int tid = threadIdx.x;
#pragma unroll
  for (int i = 0; i < 2; ++i) {
    int cid = tid + i * 256;
    int r = cid >> 3, co = (cid & 7) * 8;
    const float* p = src + (size_t)(row0 + r) * 1024 + col0 + co;
    float4 f0 = *(const float4*)(p);
    float4 f1 = *(const float4*)(p + 4);
    t[co + 0][r] = f2bf(f0.x); t[co + 1][r] = f2bf(f0.y);
    t[co + 2][r] = f2bf(f0.z); t[co + 3][r] = f2bf(f0.w);
    t[co + 4][r] = f2bf(f1.x); t[co + 5][r] = f2bf(f1.y);
    t[co + 6][r] = f2bf(f1.z); t[co + 7][r] = f2bf(f1.w);
  }
  __syncthreads();
#pragma unroll
  for (int i = 0; i < 2; ++i) {
    int cid = tid + i * 256;
    int sr = cid >> 3, cc = (cid & 7) * 8;
    bh8 val = *(const bh8*)&t[sr][cc];
    int tok = col0 + sr;
    int pr = ((tok >> 5) + 1) * 34 + (tok & 31) + 1;
    *(bh8*)(dst + (size_t)pr * 1024 + row0 + cc) = val;
  }
}

// ---------------------------------------------------------------------------
// Prep 2: Wp[tap][o][c] (bf16) = W[o][c][tap] (f32).  grid (4096, 3)
// ---------------------------------------------------------------------------
__global__ __launch_bounds__(256) void wperm3(
    const float* __restrict__ Wq, const float* __restrict__ Wk, const float* __restrict__ Wv,
    short* __restrict__ WpQ, short* __restrict__ WpK, short* __restrict__ WpV) {
  int z = blockIdx.y;
  const float* W = z == 0 ? Wq : (z == 1 ? Wk : Wv);
  short* Wp = z == 0 ? WpQ : (z == 1 ? WpK : WpV);
  int idx = blockIdx.x * 256 + threadIdx.x;  // (o,c) flat, 0..1M
  const float* wsrc = W + (size_t)idx * 9;
#pragma unroll
  for (int t = 0; t < 9; ++t) Wp[(size_t)t * 1048576 + idx] = f2bf(wsrc[t]);
}

// ---------------------------------------------------------------------------
// Prep 3: Wo f32 -> bf16 flat.  grid (1024)
// ---------------------------------------------------------------------------
__global__ __launch_bounds__(256) void cvt_bf(const float* __restrict__ src,
                                              short* __restrict__ dst) {
  int idx = (blockIdx.x * 256 + threadIdx.x) * 4;
  float4 f = *(const float4*)(src + idx);
  bh4 o; o[0] = f2bf(f.x); o[1] = f2bf(f.y); o[2] = f2bf(f.z); o[3] = f2bf(f.w);
  *(bh4*)(dst + idx) = o;
}

// ---------------------------------------------------------------------------
// Prep 4: pack mask int32 -> bits. word idx = (b*1024 + t)*32 + (s>>5)
// grid (1024), 256 thr
// ---------------------------------------------------------------------------
__global__ __launch_bounds__(256) void mask_pack(const int* __restrict__ m,
                                                 unsigned* __restrict__ mp) {
  int idx = blockIdx.x * 256 + threadIdx.x;
  const int* src = m + (size_t)idx * 32;
  unsigned wv = 0;
#pragma unroll
  for (int j = 0; j < 32; j += 4) {
    int4 a = *(const int4*)(src + j);
    wv |= ((unsigned)(a.x & 1) << j) | ((unsigned)(a.y & 1) << (j + 1)) |
          ((unsigned)(a.z & 1) << (j + 2)) | ((unsigned)(a.w & 1) << (j + 3));
  }
  mp[idx] = wv;
}

// ---------------------------------------------------------------------------
// Fused conv3x3 implicit GEMM (Q,K,V). 128x128 tile, K = 9 taps x 1024 c.
// Staging via global_load_lds (16B/lane). Halo layout -> tap shift is a pure
// pointer offset.  conv 0/1 (Q/K): out[b][o][s]; conv 2 (V): out[b][token][o].
// ---------------------------------------------------------------------------
__global__ __launch_bounds__(256) void conv_gemm_all(
    const short* __restrict__ WpQ, const short* __restrict__ WpK, const short* __restrict__ WpV,
    const short* __restrict__ xPq, const short* __restrict__ xPk, const short* __restrict__ xPv,
    short* __restrict__ cQ, short* __restrict__ cK, short* __restrict__ cVT,
    const float* __restrict__ bq, const float* __restrict__ bk, const float* __restrict__ bv,
    int convSel) {
  __shared__ short sA[4096];  // 128 rows x 32 shorts (64B), DMA-contiguous
  __shared__ short sB[4096];
  int tid = threadIdx.x, lane = tid & 63, w = tid >> 6;
  int z = blockIdx.z;
  int conv = convSel >= 0 ? convSel : (z >> 3);
  int b = convSel >= 0 ? z : (z & 7);
  const short* Wp = conv == 0 ? WpQ : (conv == 1 ? WpK : WpV);
  const short* xP = conv == 0 ? xPq : (conv == 1 ? xPk : xPv);
  short* out = conv == 0 ? cQ : (conv == 1 ? cK : cVT);
  const float* bias = conv == 0 ? bq : (conv == 1 ? bk : bv);
  int XisA = (conv == 2);
  int mbase = blockIdx.x * 128, nbase = blockIdx.y * 128;
  const short* xb = xP + (size_t)b * 1183744;
  int wbase = XisA ? nbase : mbase;  // weight-row tile base
  int sbase = XisA ? mbase : nbase;  // spatial-token tile base
  short* sW = XisA ? sB : sA;
  short* sX = XisA ? sA : sB;

  int colsh = (lane & 3) * 8;
  int ldsoff[2]; const short* wp0[2]; const short* xp0[2];
#pragma unroll
  for (int i = 0; i < 2; ++i) {
    int row = 32 * w + 16 * i + (lane >> 2);
    ldsoff[i] = (2 * w + i) * 512 + lane * 8;  // byte = chunk*1024 + lane*16
    wp0[i] = Wp + (size_t)(wbase + row) * 1024 + colsh;
    int tok = sbase + row;
    int pr0 = ((tok >> 5) + 1) * 34 + (tok & 31) + 1;
    xp0[i] = xb + (size_t)pr0 * 1024 + colsh;
  }
  f32x4 acc[4][4] = {};
  int wm = (w >> 1) * 64, wn = (w & 1) * 64;
  for (int tap = 0; tap < 9; ++tap) {
    int dOff = (tap / 3 - 1) * 34 + (tap % 3 - 1);  // padded-row shift
    size_t wtap = (size_t)tap * 1048576;
    for (int kt = 0; kt < 1024; kt += 32) {
#pragma unroll
      for (int i = 0; i < 2; ++i) {
        g2l16(wp0[i] + wtap + kt, sW + ldsoff[i]);
        g2l16(xp0[i] + (ptrdiff_t)dOff * 1024 + kt, sX + ldsoff[i]);
      }
      __syncthreads();
      bh8 af[4], bfr[4];
#pragma unroll
      for (int mt = 0; mt < 4; ++mt)
        af[mt] = *(const bh8*)&sA[(wm + mt * 16 + (lane & 15)) * 32 + (lane >> 4) * 8];
#pragma unroll
      for (int nt = 0; nt < 4; ++nt)
        bfr[nt] = *(const bh8*)&sB[(wn + nt * 16 + (lane & 15)) * 32 + (lane >> 4) * 8];
#pragma unroll
      for (int mt = 0; mt < 4; ++mt)
#pragma unroll
        for (int nt = 0; nt < 4; ++nt)
          acc[mt][nt] = __builtin_amdgcn_mfma_f32_16x16x32_bf16(af[mt], bfr[nt], acc[mt][nt], 0, 0, 0);
      __syncthreads();
    }
  }
  size_t ob = (size_t)b * 1048576;
#pragma unroll
  for (int mt = 0; mt < 4; ++mt) {
#pragma unroll
    for (int nt = 0; nt < 4; ++nt) {
      int m0 = mbase + wm + mt * 16 + ((lane >> 4) << 2);
      int n = nbase + wn + nt * 16 + (lane & 15);
#pragma unroll
      for (int r = 0; r < 4; ++r) {
        float bv = bias[XisA ? n : (m0 + r)];
        out[ob + (size_t)(m0 + r) * 1024 + n] = f2bf(acc[mt][nt][r] + bv);
      }
    }
  }
}

// ---------------------------------------------------------------------------
// Attention, SINGLE-PASS online softmax.  grid (16,16,8) = (qtile, head, b).
// Per s-tile: S^T (m=s, n=t) -> update (m,l) -> unnormalized P' to LDS ->
// rescale O by alpha (lane-remapped via shfl) -> PV accumulate.  /l at end.
// Qc,Kc: [b][tok][spatial], VT: [b][spatial][tok], AO: [b][t][h*64+j]
// ---------------------------------------------------------------------------
__global__ __launch_bounds__(256) void attn(
    const short* __restrict__ Qc, const short* __restrict__ Kc,
    const short* __restrict__ VT, const unsigned* __restrict__ Mp,
    short* __restrict__ AO) {
  __shared__ short sQ[64][72];
  __shared__ short sK[128][72];
  __shared__ short sV[64][136];
  __shared__ short sP[64][136];
  int tid = threadIdx.x, lane = tid & 63, w = tid >> 6;
  int qbase = blockIdx.x * 64, h = blockIdx.y, b = blockIdx.z;
  int j0 = h * 64;
  const short* Qb = Qc + (size_t)b * 1048576;
  const short* Kb = Kc + (size_t)b * 1048576;
  const short* Vb = VT + (size_t)b * 1048576;
  const unsigned* Mpb = Mp + (size_t)b * 32768;
  const float scale = 0.125f;  // 1/sqrt(64)

#pragma unroll
  for (int i = 0; i < 2; ++i) {
    int cid = tid + i * 256;
    int row = cid >> 3, co = (cid & 7) * 8;
    *(bh8*)&sQ[row][co] = *(const bh8*)(Qb + (size_t)(qbase + row) * 1024 + j0 + co);
  }
  __syncthreads();

  int tg = qbase + w * 16 + (lane & 15);  // stats row for this lane
  int rsel = ((lane >> 4) << 2);          // C-layout row base (quad*4)
  float mrow = -3.0e38f, lrow = 0.0f;
  f32x4 oacc[4] = {};

  for (int st = 0; st < 8; ++st) {
    // ---- stage K tile (128 s-rows x 64) and V tile (64 j-rows x 128 s) ----
#pragma unroll
    for (int i = 0; i < 4; ++i) {
      int cid = tid + i * 256;
      int row = cid >> 3, co = (cid & 7) * 8;
      *(bh8*)&sK[row][co] = *(const bh8*)(Kb + (size_t)(st * 128 + row) * 1024 + j0 + co);
      int vrow = cid >> 4, vco = (cid & 15) * 8;
      *(bh8*)&sV[vrow][vco] = *(const bh8*)(Vb + (size_t)(j0 + vrow) * 1024 + st * 128 + vco);
    }
    __syncthreads();

    // ---- S^T tile ----
    f32x4 sacc[8];
#pragma unroll
    for (int mt = 0; mt < 8; ++mt) {
      f32x4 a = {0.f, 0.f, 0.f, 0.f};
      bh8 kf = *(const bh8*)&sK[mt * 16 + (lane & 15)][(lane >> 4) * 8];
      bh8 qf = *(const bh8*)&sQ[w * 16 + (lane & 15)][(lane >> 4) * 8];
      a = __builtin_amdgcn_mfma_f32_16x16x32_bf16(kf, qf, a, 0, 0, 0);
      kf = *(const bh8*)&sK[mt * 16 + (lane & 15)][32 + (lane >> 4) * 8];
      qf = *(const bh8*)&sQ[w * 16 + (lane & 15)][32 + (lane >> 4) * 8];
      a = __builtin_amdgcn_mfma_f32_16x16x32_bf16(kf, qf, a, 0, 0, 0);
      sacc[mt] = a;
    }

    // ---- mask + scale, tile max ----
    uint4 Mw = *(const uint4*)(Mpb + (size_t)tg * 32 + st * 4);
    float tmax = -3.0e38f;
#pragma unroll
    for (int mt = 0; mt < 8; ++mt) {
      unsigned mwv = ((const unsigned*)&Mw)[mt >> 1] >> ((mt & 1) * 16 + rsel);
      f32x4 vv;
      vv[0] = (mwv & 1u) ? sacc[mt][0] * scale : -1e9f;
      vv[1] = (mwv & 2u) ? sacc[mt][1] * scale : -1e9f;
      vv[2] = (mwv & 4u) ? sacc[mt][2] * scale : -1e9f;
      vv[3] = (mwv & 8u) ? sacc[mt][3] * scale : -1e9f;
      sacc[mt] = vv;
      tmax = fmaxf(tmax, fmaxf(fmaxf(vv[0], vv[1]), fmaxf(vv[2], vv[3])));
    }
    tmax = fmaxf(tmax, __shfl_xor(tmax, 16, 64));
    tmax = fmaxf(tmax, __shfl_xor(tmax, 32, 64));
    float mnew = fmaxf(mrow, tmax);
    float alpha = __expf(fminf(mrow - mnew, 0.f));

    // ---- unnormalized P' to LDS, per-lane partial row-sums ----
    float sum = 0.f;
    uint4 Mw2 = Mw;
#pragma unroll
    for (int mt = 0; mt < 8; ++mt) {
      unsigned mwv = ((const unsigned*)&Mw2)[mt >> 1] >> ((mt & 1) * 16 + rsel);
      float p0 = (mwv & 1u) ? __expf(fminf(sacc[mt][0] - mnew, 0.f)) : 0.f;
      float p1 = (mwv & 2u) ? __expf(fminf(sacc[mt][1] - mnew, 0.f)) : 0.f;
      float p2 = (mwv & 4u) ? __expf(fminf(sacc[mt][2] - mnew, 0.f)) : 0.f;
      float p3 = (mwv & 8u) ? __expf(fminf(sacc[mt][3] - mnew, 0.f)) : 0.f;
      sum += (p0 + p1) + (p2 + p3);
      bh4 p; p[0] = f2bf(p0); p[1] = f2bf(p1); p[2] = f2bf(p2); p[3] = f2bf(p3);
      *(bh4*)&sP[w * 16 + (lane & 15)][mt * 16 + rsel] = p;
    }
    sum += __shfl_xor(sum, 16, 64);
    sum += __shfl_xor(sum, 32, 64);
    lrow = lrow * alpha + sum;
    mrow = mnew;

    // ---- rescale O by alpha (remap stats-lane -> C-layout rows) ----
    float al[4];
#pragma unroll
    for (int r = 0; r < 4; ++r) al[r] = __shfl(alpha, rsel + r, 64);
#pragma unroll
    for (int nt = 0; nt < 4; ++nt)
#pragma unroll
      for (int r = 0; r < 4; ++r) oacc[nt][r] *= al[r];
    __syncthreads();

    // ---- PV accumulate ----
#pragma unroll
    for (int k0 = 0; k0 < 4; ++k0) {
      bh8 pf = *(const bh8*)&sP[w * 16 + (lane & 15)][k0 * 32 + (lane >> 4) * 8];
#pragma unroll
      for (int nt = 0; nt < 4; ++nt) {
        bh8 vf = *(const bh8*)&sV[nt * 16 + (lane & 15)][k0 * 32 + (lane >> 4) * 8];
        oacc[nt] = __builtin_amdgcn_mfma_f32_16x16x32_bf16(pf, vf, oacc[nt], 0, 0, 0);
      }
    }
    __syncthreads();
  }

  float rl[4];
#pragma unroll
  for (int r = 0; r < 4; ++r) rl[r] = 1.0f / __shfl(lrow, rsel + r, 64);
  size_t ob = (size_t)b * 1048576;
#pragma unroll
  for (int nt = 0; nt < 4; ++nt) {
    int j = nt * 16 + (lane & 15);
    int t0 = qbase + w * 16 + rsel;
#pragma unroll
    for (int r = 0; r < 4; ++r)
      AO[ob + (size_t)(t0 + r) * 1024 + j0 + j] = f2bf(oacc[nt][r] * rl[r]);
  }
}

// ---------------------------------------------------------------------------
// Final projection: out[r][o] = sum_m A[r][m] * Wo[o][m] + bo[o]   (f32 out)
// A: [8192][1024] bf16, WoB: [1024][1024] bf16.  grid (64, 8).  DMA staging.
// ---------------------------------------------------------------------------
__global__ __launch_bounds__(256) void gemm_bt(
    const short* __restrict__ A, const short* __restrict__ Bm,
    float* __restrict__ out, const float* __restrict__ bias) {
  __shared__ short sA[4096];
  __shared__ short sB[4096];
  int tid = threadIdx.x, lane = tid & 63, w = tid >> 6;
  int mbase = blockIdx.x * 128, nbase = blockIdx.y * 128;
  int colsh = (lane & 3) * 8;
  int ldsoff[2]; const short* ap[2]; const short* bp[2];
#pragma unroll
  for (int i = 0; i < 2; ++i) {
    int row = 32 * w + 16 * i + (lane >> 2);
    ldsoff[i] = (2 * w + i) * 512 + lane * 8;
    ap[i] = A + (size_t)(mbase + row) * 1024 + colsh;
    bp[i] = Bm + (size_t)(nbase + row) * 1024 + colsh;
  }
  f32x4 acc[4][4] = {};
  int wm = (w >> 1) * 64, wn = (w & 1) * 64;
  for (int kt = 0; kt < 1024; kt += 32) {
#pragma unroll
    for (int i = 0; i < 2; ++i) {
      g2l16(ap[i] + kt, sA + ldsoff[i]);
      g2l16(bp[i] + kt, sB + ldsoff[i]);
    }
    __syncthreads();
    bh8 af[4], bfr[4];
#pragma unroll
    for (int mt = 0; mt < 4; ++mt)
      af[mt] = *(const bh8*)&sA[(wm + mt * 16 + (lane & 15)) * 32 + (lane >> 4) * 8];
#pragma unroll
    for (int nt = 0; nt < 4; ++nt)
      bfr[nt] = *(const bh8*)&sB[(wn + nt * 16 + (lane & 15)) * 32 + (lane >> 4) * 8];
#pragma unroll
    for (int mt = 0; mt < 4; ++mt)
#pragma unroll
      for (int nt = 0; nt < 4; ++nt)
        acc[mt][nt] = __builtin_amdgcn_mfma_f32_16x16x32_bf16(af[mt], bfr[nt], acc[mt][nt], 0, 0, 0);
    __syncthreads();
  }
#pragma unroll
  for (int mt = 0; mt < 4; ++mt) {
#pragma unroll
    for (int nt = 0; nt < 4; ++nt) {
      int m0 = mbase + wm + mt * 16 + ((lane >> 4) << 2);
      int n = nbase + wn + nt * 16 + (lane & 15);
      float bv = bias[n];
#pragma unroll
      for (int r = 0; r < 4; ++r)
        out[(size_t)(m0 + r) * 1024 + n] = acc[mt][nt][r] + bv;
    }
  }
}

// ---------------------------------------------------------------------------
extern "C" void kernel_launch(void* const* d_in, const int* in_sizes, int n_in,
                              void* d_out, int out_size, void* d_ws, size_t ws_size,
                              hipStream_t stream) {
  (void)in_sizes; (void)n_in; (void)out_size;
  const float* q    = (const float*)d_in[0];
  const float* k    = (const float*)d_in[1];
  const float* v    = (const float*)d_in[2];
  const float* Wq   = (const float*)d_in[3];
  const float* bq   = (const float*)d_in[4];
  const float* Wk   = (const float*)d_in[5];
  const float* bk   = (const float*)d_in[6];
  const float* Wv   = (const float*)d_in[7];
  const float* bv   = (const float*)d_in[8];
  const float* Wo   = (const float*)d_in[9];
  const float* bo   = (const float*)d_in[10];
  const int*   mask = (const int*)d_in[11];
  float* out = (float*)d_out;
  char* ws = (char*)d_ws;

  const size_t XPE = 1156ull * 1024 * 8;      // padded tensor elems (9,469,952)
  const size_t XPB = XPE * 2;                 // 18,939,904 B
  const size_t WPE = 9ull * 1048576;          // Wp elems
  short* xPq = (short*)ws;
  short* xPk = xPq + XPE;
  short* xPv = xPk + XPE;
  short* WpQ = (short*)(ws + 3 * XPB);
  short* WpK = WpQ + WPE;
  short* WpV = WpK + WPE;
  char* p2 = ws + 3 * XPB + 3 * WPE * 2;      // 113,442,816

  bool fused = ws_size >= 167000000ull;
  short *cQ, *cK, *cVT, *WoB, *AO; unsigned* Mpk;
  if (fused) {
    cQ  = (short*)(p2);
    cK  = (short*)(p2 + 16777216);
    cVT = (short*)(p2 + 33554432);
    WoB = (short*)(p2 + 50331648);
    Mpk = (unsigned*)(p2 + 52428800);
    AO  = xPq;                                 // dead after conv (hi-water ~159.3MB)
  } else {
    cQ  = (short*)(p2);
    WoB = (short*)(p2 + 16777216);
    Mpk = (unsigned*)(p2 + 18874368);
    cK  = xPq;   // sequential: xPq dead after conv Q
    cVT = xPk;   // xPk dead after conv K
    AO  = xPv;   // xPv dead after conv V      (hi-water ~127.2MB)
  }

  zero_halo<<<dim3(66, 24), dim3(256), 0, stream>>>(xPq);
  transpose3<<<dim3(16, 16, 24), dim3(256), 0, stream>>>(q, k, v, xPq, xPk, xPv);
  wperm3<<<dim3(4096, 3), dim3(256), 0, stream>>>(Wq, Wk, Wv, WpQ, WpK, WpV);
  cvt_bf<<<dim3(1024), dim3(256), 0, stream>>>(Wo, WoB);
  mask_pack<<<dim3(1024), dim3(256), 0, stream>>>(mask, Mpk);
  if (fused) {
    conv_gemm_all<<<dim3(8, 8, 24), dim3(256), 0, stream>>>(
        WpQ, WpK, WpV, xPq, xPk, xPv, cQ, cK, cVT, bq, bk, bv, -1);
  } else {
    conv_gemm_all<<<dim3(8, 8, 8), dim3(256), 0, stream>>>(
        WpQ, WpK, WpV, xPq, xPk, xPv, cQ, cK, cVT, bq, bk, bv, 0);
    conv_gemm_all<<<dim3(8, 8, 8), dim3(256), 0, stream>>>(
        WpQ, WpK, WpV, xPq, xPk, xPv, cQ, cK, cVT, bq, bk, bv, 1);
    conv_gemm_all<<<dim3(8, 8, 8), dim3(256), 0, stream>>>(
        WpQ, WpK, WpV, xPq, xPk, xPv, cQ, cK, cVT, bq, bk, bv, 2);
  }
  attn<<<dim3(16, 16, 8), dim3(256), 0, stream>>>(cQ, cK, cVT, Mpk, AO);
  gemm_bt<<<dim3(64, 8), dim3(256), 0, stream>>>(AO, WoB, out, bo);
}